// Round 5
// baseline (75.458 us; speedup 1.0000x reference)
//
#include <hip/hip_runtime.h>

typedef float v2f __attribute__((ext_vector_type(2)));

#define DEV static __device__ __forceinline__

// xor16 across the 16-lane rows of a 32-lane group (LDS pipe)
DEV float swz_xor16(float v) {
  return __int_as_float(__builtin_amdgcn_ds_swizzle(__float_as_int(v), 0x401F));
}

// one fused dpp-add line for operand n
#define DL(n, ctrl) \
  "v_add_f32_dpp %" #n ", %" #n ", %" #n " " ctrl " row_mask:0xf bank_mask:0xf\n\t"

#define ST16(c) DL(0,c) DL(1,c) DL(2,c) DL(3,c) DL(4,c) DL(5,c) DL(6,c) DL(7,c) \
                DL(8,c) DL(9,c) DL(10,c) DL(11,c) DL(12,c) DL(13,c) DL(14,c) DL(15,c)
#define ST8(c)  DL(0,c) DL(1,c) DL(2,c) DL(3,c) DL(4,c) DL(5,c) DL(6,c) DL(7,c)

// 16 interleaved butterfly chains, 4 DPP stages each (xor1,xor2,~xor4,~xor8).
// Interleave distance >> 2-cycle VALU->DPP hazard; s_nop 1 guards entry.
DEV void dpp4x16(float& r0, float& r1, float& r2, float& r3,
                 float& r4, float& r5, float& r6, float& r7,
                 float& r8, float& r9, float& r10, float& r11,
                 float& r12, float& r13, float& r14, float& r15) {
  asm("s_nop 1\n\t"
      ST16("quad_perm:[1,0,3,2]")
      ST16("quad_perm:[2,3,0,1]")
      ST16("row_half_mirror")
      ST16("row_mirror")
      : "+v"(r0), "+v"(r1), "+v"(r2), "+v"(r3),
        "+v"(r4), "+v"(r5), "+v"(r6), "+v"(r7),
        "+v"(r8), "+v"(r9), "+v"(r10), "+v"(r11),
        "+v"(r12), "+v"(r13), "+v"(r14), "+v"(r15));
}

DEV void dpp4x8(float& r0, float& r1, float& r2, float& r3,
                float& r4, float& r5, float& r6, float& r7) {
  asm("s_nop 1\n\t"
      ST8("quad_perm:[1,0,3,2]")
      ST8("quad_perm:[2,3,0,1]")
      ST8("row_half_mirror")
      ST8("row_mirror")
      : "+v"(r0), "+v"(r1), "+v"(r2), "+v"(r3),
        "+v"(r4), "+v"(r5), "+v"(r6), "+v"(r7));
}

// DPP move with bound_ctrl (OOB -> 0); compiler-managed hazards.
template<int CTRL>
DEV float dpp_movf(float v) {
  return __int_as_float(__builtin_amdgcn_update_dpp(
      0, __float_as_int(v), CTRL, 0xF, 0xF, true));
}

// gelu via tanh-form with Pade(3,2) tanh + med3 clamp (no v_exp):
// w = 0.79788456*(x + 0.044715 x^3); tanh(w) ~= clamp(w(27+w^2)/(27+9w^2), -1, 1)
// max |gelu err| ~0.023 (budget 0.4125). 10 pk + 2 med3 + 2 rcp.
DEV v2f gelu2(v2f x) {
  v2f x2  = x * x;
  v2f c   = x2 * 0.0356774081f + 0.7978845608f;
  v2f w   = x * c;
  v2f w2  = w * w;
  v2f a   = w2 + 27.0f;
  v2f num = w * a;
  v2f den = w2 * 9.0f + 27.0f;
  v2f r   = { __builtin_amdgcn_rcpf(den.x), __builtin_amdgcn_rcpf(den.y) };
  v2f th  = num * r;
  asm("v_med3_f32 %0, %1, -1.0, 1.0" : "=v"(th.x) : "v"(th.x));
  asm("v_med3_f32 %0, %1, -1.0, 1.0" : "=v"(th.y) : "v"(th.y));
  v2f hx  = x * 0.5f;
  return hx * th + hx;
}

// setup: reorder conv weights into input-channel-pair v2f:
// P[(o*2+cp)*5+k] = { w[o][2cp][k], w[o][2cp+1][k] }  (40 pairs, 320 B)
__global__ void pack_conv(const float* __restrict__ cw, float* __restrict__ ws) {
  int t = threadIdx.x;
  if (t < 40) {
    int k = t % 5, cp = (t / 5) & 1, o = t / 10;
    ws[2 * t]     = cw[(o * 4 + 2 * cp) * 5 + k];
    ws[2 * t + 1] = cw[(o * 4 + 2 * cp + 1) * 5 + k];
  }
}

template<bool PACKED>
__global__ void __launch_bounds__(256) gmlp_fused(
    const float* __restrict__ x,
    const float* __restrict__ ln1_g, const float* __restrict__ ln1_b,
    const float* __restrict__ W1, const float* __restrict__ b1,
    const float* __restrict__ sgu_g, const float* __restrict__ sgu_b,
    const float* __restrict__ conv_w, const float* __restrict__ conv_b,
    const float* __restrict__ W2, const float* __restrict__ b2,
    const float* __restrict__ cwp,   // packed conv weights in d_ws (v2f x40)
    float* __restrict__ out, int nsamp)
{
  const int pos = threadIdx.x & 31;
  const int grp = threadIdx.x >> 5;
  const int gpb = blockDim.x >> 5;

  const float g1 = ln1_g[pos], be1 = ln1_b[pos];
  const float g2 = sgu_g[pos], be2 = sgu_b[pos];
  const v2f g1v = { g1, g1 }, b1v = { be1, be1 };
  const v2f g2v = { g2, g2 }, b2v = { be2, be2 };

  const float fm1 = (pos >= 1) ? 1.0f : 0.0f;
  const float fm2 = (pos >= 2) ? 1.0f : 0.0f;
  const float fp1 = (pos <= 30) ? 1.0f : 0.0f;
  const float fp2 = (pos <= 29) ? 1.0f : 0.0f;
  const v2f mm1 = { fm1, fm1 }, mm2 = { fm2, fm2 };
  const v2f mp1 = { fp1, fp1 }, mp2 = { fp2, fp2 };

  const v2f* __restrict__ W1v = (const v2f*)W1;   // W1v[o*4+p]
  const v2f* __restrict__ W2v = (const v2f*)W2;   // W2v[o*2+p]
  const v2f* __restrict__ Pk  = (const v2f*)cwp;  // Pk[(o*2+cp)*5+k]

  for (int s = blockIdx.x * gpb + grp; s < nsamp; s += gridDim.x * gpb) {
    const float* xs = x + (size_t)s * 256 + pos;

    v2f res2[4];
#pragma unroll
    for (int p = 0; p < 4; ++p) res2[p] = v2f{ xs[(2*p)*32], xs[(2*p+1)*32] };

    // ---- LN1: 16 chains (8 ch x {sum, sumsq}) batched ----
    float r[16], t[16];
#pragma unroll
    for (int p = 0; p < 4; ++p) {
      v2f sq = res2[p] * res2[p];
      r[2*p]   = res2[p].x; r[2*p+1] = res2[p].y;
      r[8+2*p] = sq.x;      r[9+2*p] = sq.y;
    }
#pragma unroll
    for (int i = 0; i < 16; ++i) t[i] = swz_xor16(r[i]);
#pragma unroll
    for (int i = 0; i < 16; ++i) r[i] += t[i];
    dpp4x16(r[0], r[1], r[2], r[3], r[4], r[5], r[6], r[7],
            r[8], r[9], r[10], r[11], r[12], r[13], r[14], r[15]);

    v2f h[4];
#pragma unroll
    for (int p = 0; p < 4; ++p) {
      v2f s1 = { r[2*p], r[2*p+1] }, s2 = { r[8+2*p], r[9+2*p] };
      v2f mu  = s1 * 0.03125f;
      v2f var = s2 * 0.03125f - mu * mu;
      v2f ve  = var + 1e-5f;
      v2f rs  = { __builtin_amdgcn_rsqf(ve.x), __builtin_amdgcn_rsqf(ve.y) };
      v2f A = rs * g1v;
      v2f B = b1v - mu * A;
      h[p] = res2[p] * A + B;
    }

    // ---- channel-mix matmul (8x8) packed + bias ----
    float uo[8];
#pragma unroll
    for (int o = 0; o < 8; ++o) {
      v2f acc = h[0] * W1v[o*4 + 0];
      acc = h[1] * W1v[o*4 + 1] + acc;
      acc = h[2] * W1v[o*4 + 2] + acc;
      acc = h[3] * W1v[o*4 + 3] + acc;
      uo[o] = acc.x + acc.y + b1[o];
    }
    v2f t01 = gelu2(v2f{ uo[0], uo[1] });
    v2f t23 = gelu2(v2f{ uo[2], uo[3] });
    v2f t45 = gelu2(v2f{ uo[4], uo[5] });
    v2f t67 = gelu2(v2f{ uo[6], uo[7] });

    // ---- SGU LN2: 8 chains (4 ch x {sum, sumsq}) batched ----
    float q[8], tq[8];
    {
      v2f sq0 = t45 * t45, sq1 = t67 * t67;
      q[0] = t45.x; q[1] = t45.y; q[2] = t67.x; q[3] = t67.y;
      q[4] = sq0.x; q[5] = sq0.y; q[6] = sq1.x; q[7] = sq1.y;
    }
#pragma unroll
    for (int i = 0; i < 8; ++i) tq[i] = swz_xor16(q[i]);
#pragma unroll
    for (int i = 0; i < 8; ++i) q[i] += tq[i];
    dpp4x8(q[0], q[1], q[2], q[3], q[4], q[5], q[6], q[7]);

    v2f vl[2];
#pragma unroll
    for (int p = 0; p < 2; ++p) {
      v2f val = (p == 0) ? t45 : t67;
      v2f s1 = { q[2*p], q[2*p+1] }, s2 = { q[4+2*p], q[5+2*p] };
      v2f mu  = s1 * 0.03125f;
      v2f var = s2 * 0.03125f - mu * mu;
      v2f ve  = var + 1e-5f;
      v2f rs  = { __builtin_amdgcn_rsqf(ve.x), __builtin_amdgcn_rsqf(ve.y) };
      v2f A = rs * g2v;
      v2f B = b2v - mu * A;
      vl[p] = val * A + B;
    }

    // ---- conv taps via DPP wave shifts, masked ----
    v2f cm1[2], cm2[2], cp1[2], cp2[2];
#pragma unroll
    for (int p = 0; p < 2; ++p) {
      v2f a = v2f{ dpp_movf<0x138>(vl[p].x),  dpp_movf<0x138>(vl[p].y)  } * mm1; // pos-1
      cm1[p] = a;
      cm2[p] = v2f{ dpp_movf<0x138>(a.x),     dpp_movf<0x138>(a.y)      } * mm2; // pos-2
      v2f d = v2f{ dpp_movf<0x130>(vl[p].x),  dpp_movf<0x130>(vl[p].y)  } * mp1; // pos+1
      cp1[p] = d;
      cp2[p] = v2f{ dpp_movf<0x130>(d.x),     dpp_movf<0x130>(d.y)      } * mp2; // pos+2
    }

    // ---- conv (4 out, 4 in, 5 taps) + bias, gate with u ----
    const float uu[4] = { t01.x, t01.y, t23.x, t23.y };
    float gte[4];
    if constexpr (PACKED) {
#pragma unroll
      for (int o = 0; o < 4; ++o) {
        v2f acc = cm2[0] * Pk[(o*2+0)*5 + 0];
        acc = cm1[0] * Pk[(o*2+0)*5 + 1] + acc;
        acc = vl [0] * Pk[(o*2+0)*5 + 2] + acc;
        acc = cp1[0] * Pk[(o*2+0)*5 + 3] + acc;
        acc = cp2[0] * Pk[(o*2+0)*5 + 4] + acc;
        acc = cm2[1] * Pk[(o*2+1)*5 + 0] + acc;
        acc = cm1[1] * Pk[(o*2+1)*5 + 1] + acc;
        acc = vl [1] * Pk[(o*2+1)*5 + 2] + acc;
        acc = cp1[1] * Pk[(o*2+1)*5 + 3] + acc;
        acc = cp2[1] * Pk[(o*2+1)*5 + 4] + acc;
        gte[o] = uu[o] * (acc.x + acc.y + conv_b[o]);
      }
    } else {
#pragma unroll
      for (int o = 0; o < 4; ++o) {
        float acc = conv_b[o];
#pragma unroll
        for (int c = 0; c < 4; ++c) {
          const float* w = conv_w + (o * 4 + c) * 5;
          float vm2 = (c & 1) ? cm2[c>>1].y : cm2[c>>1].x;
          float vm1 = (c & 1) ? cm1[c>>1].y : cm1[c>>1].x;
          float v0  = (c & 1) ? vl [c>>1].y : vl [c>>1].x;
          float vp1 = (c & 1) ? cp1[c>>1].y : cp1[c>>1].x;
          float vp2 = (c & 1) ? cp2[c>>1].y : cp2[c>>1].x;
          acc = __builtin_fmaf(vm2, w[0], acc);
          acc = __builtin_fmaf(vm1, w[1], acc);
          acc = __builtin_fmaf(v0,  w[2], acc);
          acc = __builtin_fmaf(vp1, w[3], acc);
          acc = __builtin_fmaf(vp2, w[4], acc);
        }
        gte[o] = uu[o] * acc;
      }
    }

    // ---- out matmul (4->8) packed + gelu + residual, NT store ----
    const v2f gv0 = { gte[0], gte[1] }, gv1 = { gte[2], gte[3] };
    float oo[8];
#pragma unroll
    for (int o = 0; o < 8; ++o) {
      v2f acc = gv0 * W2v[o*2 + 0];
      acc = gv1 * W2v[o*2 + 1] + acc;
      oo[o] = acc.x + acc.y + b2[o];
    }
    float* os = out + (size_t)s * 256 + pos;
#pragma unroll
    for (int p = 0; p < 4; ++p) {
      v2f g = gelu2(v2f{ oo[2*p], oo[2*p+1] }) + res2[p];
      __builtin_nontemporal_store(g.x, os + (2*p)*32);
      __builtin_nontemporal_store(g.y, os + (2*p+1)*32);
    }
  }
}

extern "C" void kernel_launch(void* const* d_in, const int* in_sizes, int n_in,
                              void* d_out, int out_size, void* d_ws, size_t ws_size,
                              hipStream_t stream) {
  const float* x      = (const float*)d_in[0];
  const float* ln1_g  = (const float*)d_in[1];
  const float* ln1_b  = (const float*)d_in[2];
  const float* W1     = (const float*)d_in[3];
  const float* b1     = (const float*)d_in[4];
  const float* sgu_g  = (const float*)d_in[5];
  const float* sgu_b  = (const float*)d_in[6];
  const float* conv_w = (const float*)d_in[7];
  const float* conv_b = (const float*)d_in[8];
  const float* W2     = (const float*)d_in[9];
  const float* b2     = (const float*)d_in[10];
  float* out = (float*)d_out;

  int nsamp = in_sizes[0] / 256;
  // exact grid: 8 samples per 256-thread block, single loop trip
  int nblocks = (nsamp + 7) / 8;
  if (nblocks < 1) nblocks = 1;

  const bool packed = (ws_size >= 320);
  if (packed) {
    hipLaunchKernelGGL(pack_conv, dim3(1), dim3(64), 0, stream,
                       conv_w, (float*)d_ws);
    hipLaunchKernelGGL((gmlp_fused<true>), dim3(nblocks), dim3(256), 0, stream,
                       x, ln1_g, ln1_b, W1, b1, sgu_g, sgu_b,
                       conv_w, conv_b, W2, b2, (const float*)d_ws, out, nsamp);
  } else {
    hipLaunchKernelGGL((gmlp_fused<false>), dim3(nblocks), dim3(256), 0, stream,
                       x, ln1_g, ln1_b, W1, b1, sgu_g, sgu_b,
                       conv_w, conv_b, W2, b2, (const float*)d_ws, out, nsamp);
  }
}

// Round 6
// 55.346 us; speedup vs baseline: 1.3634x; 1.3634x over previous
//
#include <hip/hip_runtime.h>

typedef float v2f __attribute__((ext_vector_type(2)));
typedef float v4f __attribute__((ext_vector_type(4)));

#define DEV static __device__ __forceinline__

// one fused dpp-add line for operand n
#define DL(n, ctrl) \
  "v_add_f32_dpp %" #n ", %" #n ", %" #n " " ctrl " row_mask:0xf bank_mask:0xf\n\t"

#define ST16(c) DL(0,c) DL(1,c) DL(2,c) DL(3,c) DL(4,c) DL(5,c) DL(6,c) DL(7,c) \
                DL(8,c) DL(9,c) DL(10,c) DL(11,c) DL(12,c) DL(13,c) DL(14,c) DL(15,c)
#define ST8(c)  DL(0,c) DL(1,c) DL(2,c) DL(3,c) DL(4,c) DL(5,c) DL(6,c) DL(7,c)

// Butterfly all-reduce over each 8-lane group (sample), 16 interleaved chains.
// Stages: xor1, xor2, then half-mirror (acts as xor4 once quads are uniform).
// Interleave distance 16 >> 2-cycle VALU->DPP hazard; s_nop 1 guards entry.
DEV void dpp3x16(float& r0, float& r1, float& r2, float& r3,
                 float& r4, float& r5, float& r6, float& r7,
                 float& r8, float& r9, float& r10, float& r11,
                 float& r12, float& r13, float& r14, float& r15) {
  asm("s_nop 1\n\t"
      ST16("quad_perm:[1,0,3,2]")
      ST16("quad_perm:[2,3,0,1]")
      ST16("row_half_mirror")
      : "+v"(r0), "+v"(r1), "+v"(r2), "+v"(r3),
        "+v"(r4), "+v"(r5), "+v"(r6), "+v"(r7),
        "+v"(r8), "+v"(r9), "+v"(r10), "+v"(r11),
        "+v"(r12), "+v"(r13), "+v"(r14), "+v"(r15));
}

DEV void dpp3x8(float& r0, float& r1, float& r2, float& r3,
                float& r4, float& r5, float& r6, float& r7) {
  asm("s_nop 1\n\t"
      ST8("quad_perm:[1,0,3,2]")
      ST8("quad_perm:[2,3,0,1]")
      ST8("row_half_mirror")
      : "+v"(r0), "+v"(r1), "+v"(r2), "+v"(r3),
        "+v"(r4), "+v"(r5), "+v"(r6), "+v"(r7));
}

// DPP move with bound_ctrl (OOB -> 0); compiler-managed hazards.
template<int CTRL>
DEV float dpp_movf(float v) {
  return __int_as_float(__builtin_amdgcn_update_dpp(
      0, __float_as_int(v), CTRL, 0xF, 0xF, true));
}

// gelu via tanh-form with Pade(3,2) tanh + med3 clamp (no v_exp):
// w = 0.79788456*(x + 0.044715 x^3); tanh(w) ~= clamp(w(27+w^2)/(27+9w^2),-1,1)
// max |gelu err| ~0.023 (budget 0.4125).
DEV v2f gelu2(v2f x) {
  v2f x2  = x * x;
  v2f c   = x2 * 0.0356774081f + 0.7978845608f;
  v2f w   = x * c;
  v2f w2  = w * w;
  v2f num = w * (w2 + 27.0f);
  v2f den = w2 * 9.0f + 27.0f;
  v2f r   = { __builtin_amdgcn_rcpf(den.x), __builtin_amdgcn_rcpf(den.y) };
  v2f th  = num * r;
  asm("v_med3_f32 %0, %1, -1.0, 1.0" : "=v"(th.x) : "v"(th.x));
  asm("v_med3_f32 %0, %1, -1.0, 1.0" : "=v"(th.y) : "v"(th.y));
  v2f hx  = x * 0.5f;
  return hx * th + hx;
}

__global__ void __launch_bounds__(256) gmlp_fused(
    const float* __restrict__ x,
    const float* __restrict__ ln1_g, const float* __restrict__ ln1_b,
    const float* __restrict__ W1, const float* __restrict__ b1,
    const float* __restrict__ sgu_g, const float* __restrict__ sgu_b,
    const float* __restrict__ conv_w, const float* __restrict__ conv_b,
    const float* __restrict__ W2, const float* __restrict__ b2,
    float* __restrict__ out, int nsamp)
{
  const int l  = threadIdx.x & 7;     // lane-in-sample: owns positions 4l..4l+3
  const int sg = threadIdx.x >> 3;    // sample within block (32 per block)
  const int s  = blockIdx.x * 32 + sg;
  if (s >= nsamp) return;

  const int p0 = l * 4;

  // per-position LN affine constants (this lane's 4 positions), as pairs
  const v4f g1q = *(const v4f*)(ln1_g + p0);
  const v4f c1bq = *(const v4f*)(ln1_b + p0);
  const v4f g2q = *(const v4f*)(sgu_g + p0);
  const v4f c2bq = *(const v4f*)(sgu_b + p0);
  const v2f c1g[2] = { {g1q.x, g1q.y}, {g1q.z, g1q.w} };
  const v2f c1b[2] = { {c1bq.x, c1bq.y}, {c1bq.z, c1bq.w} };
  const v2f c2g[2] = { {g2q.x, g2q.y}, {g2q.z, g2q.w} };
  const v2f c2b[2] = { {c2bq.x, c2bq.y}, {c2bq.z, c2bq.w} };

  // halo masks: left halo valid only if l>=1 (else zero-pad), right if l<=6
  const float fl = (l >= 1) ? 1.0f : 0.0f;
  const float fr = (l <= 6) ? 1.0f : 0.0f;

  // ---- load x: 8 channels x 4 positions (dwordx4 each); x is the residual ----
  const float* xs = x + (size_t)s * 256 + p0;
  v2f xv[8][2];
#pragma unroll
  for (int c = 0; c < 8; ++c) {
    v4f q = *(const v4f*)(xs + c * 32);
    xv[c][0] = v2f{ q.x, q.y };
    xv[c][1] = v2f{ q.z, q.w };
  }

  // ---- LN1: local pre-reduce (packed) then 3-stage DPP butterfly ----
  float r[16];
#pragma unroll
  for (int c = 0; c < 8; ++c) {
    v2f sp = xv[c][0] + xv[c][1];
    v2f qp = xv[c][0] * xv[c][0];
    qp = xv[c][1] * xv[c][1] + qp;
    r[c]     = sp.x + sp.y;
    r[8 + c] = qp.x + qp.y;
  }
  dpp3x16(r[0], r[1], r[2], r[3], r[4], r[5], r[6], r[7],
          r[8], r[9], r[10], r[11], r[12], r[13], r[14], r[15]);

  v2f h[8][2];
#pragma unroll
  for (int c = 0; c < 8; ++c) {
    float mu  = r[c] * 0.03125f;
    float var = __builtin_fmaf(r[8 + c], 0.03125f, -mu * mu);
    float rs  = __builtin_amdgcn_rsqf(var + 1e-5f);
    v2f A0 = c1g[0] * rs, A1 = c1g[1] * rs;
    v2f B0 = c1b[0] - A0 * mu, B1 = c1b[1] - A1 * mu;
    h[c][0] = xv[c][0] * A0 + B0;
    h[c][1] = xv[c][1] * A1 + B1;
  }

  // ---- channel-mix matmul (8x8, lane-local over position pairs) + gelu ----
  v2f t[8][2];
#pragma unroll
  for (int o = 0; o < 8; ++o) {
    float bo = b1[o];
    v2f a0 = { bo, bo }, a1 = { bo, bo };
#pragma unroll
    for (int c = 0; c < 8; ++c) {
      float wv = W1[o * 8 + c];
      a0 = h[c][0] * wv + a0;
      a1 = h[c][1] * wv + a1;
    }
    t[o][0] = gelu2(a0);
    t[o][1] = gelu2(a1);
  }

  // ---- SGU LN2 on channels 4..7 ----
  float q[8];
#pragma unroll
  for (int c = 0; c < 4; ++c) {
    v2f sp = t[4 + c][0] + t[4 + c][1];
    v2f qp = t[4 + c][0] * t[4 + c][0];
    qp = t[4 + c][1] * t[4 + c][1] + qp;
    q[c]     = sp.x + sp.y;
    q[4 + c] = qp.x + qp.y;
  }
  dpp3x8(q[0], q[1], q[2], q[3], q[4], q[5], q[6], q[7]);

  // extended position array per channel: [haloL0 haloL1 v0 v1 v2 v3 haloR0 haloR1]
  float e[4][8];
#pragma unroll
  for (int c = 0; c < 4; ++c) {
    float mu  = q[c] * 0.03125f;
    float var = __builtin_fmaf(q[4 + c], 0.03125f, -mu * mu);
    float rs  = __builtin_amdgcn_rsqf(var + 1e-5f);
    v2f A0 = c2g[0] * rs, A1 = c2g[1] * rs;
    v2f B0 = c2b[0] - A0 * mu, B1 = c2b[1] - A1 * mu;
    v2f v0 = t[4 + c][0] * A0 + B0;
    v2f v1 = t[4 + c][1] * A1 + B1;
    e[c][2] = v0.x; e[c][3] = v0.y; e[c][4] = v1.x; e[c][5] = v1.y;
  }
  // halos via wave shifts: lane l-1 holds positions 4l-2,4l-1 (its v2,v3);
  // lane l+1 holds 4l+4,4l+5 (its v0,v1). Sample-boundary leakage killed by fl/fr.
#pragma unroll
  for (int c = 0; c < 4; ++c) {
    e[c][0] = dpp_movf<0x138>(e[c][4]) * fl;   // wave_shr1
    e[c][1] = dpp_movf<0x138>(e[c][5]) * fl;
    e[c][6] = dpp_movf<0x130>(e[c][2]) * fr;   // wave_shl1
    e[c][7] = dpp_movf<0x130>(e[c][3]) * fr;
  }

  // ---- conv (4 out, 4 in, 5 taps, correlation) + bias, gate with u ----
  float gsc[4][4];
#pragma unroll
  for (int o = 0; o < 4; ++o) {
#pragma unroll
    for (int k = 0; k < 4; ++k) {
      float acc = conv_b[o];
#pragma unroll
      for (int c = 0; c < 4; ++c) {
        const float* w = conv_w + (o * 4 + c) * 5;
        acc = __builtin_fmaf(e[c][k],     w[0], acc);
        acc = __builtin_fmaf(e[c][k + 1], w[1], acc);
        acc = __builtin_fmaf(e[c][k + 2], w[2], acc);
        acc = __builtin_fmaf(e[c][k + 3], w[3], acc);
        acc = __builtin_fmaf(e[c][k + 4], w[4], acc);
      }
      float u = (k < 2) ? ((k & 1) ? t[o][0].y : t[o][0].x)
                        : ((k & 1) ? t[o][1].y : t[o][1].x);
      gsc[o][k] = u * acc;
    }
  }
  v2f gp[4][2];
#pragma unroll
  for (int c = 0; c < 4; ++c) {
    gp[c][0] = v2f{ gsc[c][0], gsc[c][1] };
    gp[c][1] = v2f{ gsc[c][2], gsc[c][3] };
  }

  // ---- out matmul (4->8) + gelu + residual, NT dwordx4 store ----
  float* os = out + (size_t)s * 256 + p0;
#pragma unroll
  for (int o = 0; o < 8; ++o) {
    float bo = b2[o];
    v2f a0 = { bo, bo }, a1 = { bo, bo };
#pragma unroll
    for (int c = 0; c < 4; ++c) {
      float wv = W2[o * 4 + c];
      a0 = gp[c][0] * wv + a0;
      a1 = gp[c][1] * wv + a1;
    }
    v2f o0 = gelu2(a0) + xv[o][0];
    v2f o1 = gelu2(a1) + xv[o][1];
    v4f ov = { o0.x, o0.y, o1.x, o1.y };
    __builtin_nontemporal_store(ov, (v4f*)(os + o * 32));
  }
}

extern "C" void kernel_launch(void* const* d_in, const int* in_sizes, int n_in,
                              void* d_out, int out_size, void* d_ws, size_t ws_size,
                              hipStream_t stream) {
  const float* x      = (const float*)d_in[0];
  const float* ln1_g  = (const float*)d_in[1];
  const float* ln1_b  = (const float*)d_in[2];
  const float* W1     = (const float*)d_in[3];
  const float* b1     = (const float*)d_in[4];
  const float* sgu_g  = (const float*)d_in[5];
  const float* sgu_b  = (const float*)d_in[6];
  const float* conv_w = (const float*)d_in[7];
  const float* conv_b = (const float*)d_in[8];
  const float* W2     = (const float*)d_in[9];
  const float* b2     = (const float*)d_in[10];
  float* out = (float*)d_out;

  int nsamp = in_sizes[0] / 256;        // 131072 samples of 8x32
  int nblocks = (nsamp + 31) / 32;      // 32 samples per 256-thread block
  if (nblocks < 1) nblocks = 1;

  hipLaunchKernelGGL(gmlp_fused, dim3(nblocks), dim3(256), 0, stream,
                     x, ln1_g, ln1_b, W1, b1, sgu_g, sgu_b,
                     conv_w, conv_b, W2, b2, out, nsamp);
}